// Round 8
// baseline (157.282 us; speedup 1.0000x reference)
//
#include <hip/hip_runtime.h>

#define T_TOK 1024
#define H_DIM 1024
#define I_DIM 768
#define E_NUM 8

// prep ranges (in 8-element groups)
#define G13 1572864   // 8*1536*1024/8
#define G2   786432   // 8*1024*768/8
#define GX   131072   // 1024*1024/8
#define GTOT 2621440  // G13+G2+GX+GO (GO=131072)
#define GHALF 1310720

typedef __bf16 bf16x8 __attribute__((ext_vector_type(8)));
typedef float  f32x4  __attribute__((ext_vector_type(4)));

__device__ inline bf16x8 cvt8(float4 a, float4 b, float s) {
    bf16x8 o;
    o[0] = (__bf16)(a.x * s); o[1] = (__bf16)(a.y * s);
    o[2] = (__bf16)(a.z * s); o[3] = (__bf16)(a.w * s);
    o[4] = (__bf16)(b.x * s); o[5] = (__bf16)(b.y * s);
    o[6] = (__bf16)(b.z * s); o[7] = (__bf16)(b.w * s);
    return o;
}

// ---- prep + router fused -------------------------------------------------
__device__ inline void prep_group(
    int g,
    const float* __restrict__ w13, const float* __restrict__ w13s,
    const float* __restrict__ w2,  const float* __restrict__ w2s,
    const float* __restrict__ x,   float4* __restrict__ out4,
    __bf16* __restrict__ w13d, __bf16* __restrict__ w2d, __bf16* __restrict__ xbf)
{
    if (g < G13) {
        int k8 = g & 127;               // 128 groups per 1024-k row
        int row = g >> 7;               // e*1536 + n
        float s = w13s[(row << 3) | (k8 >> 4)];
        const float4* src = (const float4*)w13 + (size_t)g * 2;
        *(bf16x8*)(w13d + (size_t)g * 8) = cvt8(src[0], src[1], s);
    } else if (g < G13 + G2) {
        int g2 = g - G13;
        unsigned row = (unsigned)g2 / 96u;   // e*1024 + h (96 groups per 768-k row)
        int k8 = g2 - row * 96;
        float s = w2s[row * 6 + (k8 >> 4)];
        const float4* src = (const float4*)w2 + (size_t)g2 * 2;
        *(bf16x8*)(w2d + (size_t)g2 * 8) = cvt8(src[0], src[1], s);
    } else if (g < G13 + G2 + GX) {
        int gx = g - (G13 + G2);
        const float4* src = (const float4*)x + (size_t)gx * 2;
        *(bf16x8*)(xbf + (size_t)gx * 8) = cvt8(src[0], src[1], 1.0f);
    } else {
        int go = g - (G13 + G2 + GX);
        float4 z = make_float4(0.f, 0.f, 0.f, 0.f);
        out4[2 * go] = z; out4[2 * go + 1] = z;
    }
}

__global__ __launch_bounds__(256) void prep_kernel(
    const float* __restrict__ w13, const float* __restrict__ w13s,
    const float* __restrict__ w2,  const float* __restrict__ w2s,
    const float* __restrict__ x,   float4* __restrict__ out4,
    __bf16* __restrict__ w13d, __bf16* __restrict__ w2d, __bf16* __restrict__ xbf,
    const float* __restrict__ logits,
    int* __restrict__ counts, int* __restrict__ base,
    int* __restrict__ tok_list, float* __restrict__ wt_list)
{
    const int bx = blockIdx.x, tid = threadIdx.x;
    if (bx < 5120) {
        int g0 = bx * 256 + tid;        // [0, GHALF): always in w13 range
        prep_group(g0, w13, w13s, w2, w2s, x, out4, w13d, w2d, xbf);
        prep_group(g0 + GHALF, w13, w13s, w2, w2s, x, out4, w13d, w2d, xbf);
        return;
    }
    // ---- router block (bx == 5120): top-2 of 8, renormalized weights ----
    __shared__ int cnt[E_NUM];
    if (tid < E_NUM) cnt[tid] = 0;
    __syncthreads();
#pragma unroll
    for (int tt = 0; tt < 4; tt++) {
        int t = tid + tt * 256;
        float l[E_NUM];
#pragma unroll
        for (int e = 0; e < E_NUM; e++) l[e] = logits[t * E_NUM + e];
        int e0 = 0; float m0 = l[0];
#pragma unroll
        for (int e = 1; e < E_NUM; e++) if (l[e] > m0) { m0 = l[e]; e0 = e; }
        int e1 = -1; float m1 = -3e38f;
#pragma unroll
        for (int e = 0; e < E_NUM; e++) if (e != e0 && l[e] > m1) { m1 = l[e]; e1 = e; }
        float w0 = 1.0f / (1.0f + expf(m1 - m0));
        float w1 = 1.0f - w0;
        int p0 = atomicAdd(&cnt[e0], 1);
        tok_list[e0 * T_TOK + p0] = t;
        wt_list[e0 * T_TOK + p0] = w0;
        int p1 = atomicAdd(&cnt[e1], 1);
        tok_list[e1 * T_TOK + p1] = t;
        wt_list[e1 * T_TOK + p1] = w1;
    }
    __syncthreads();
    if (tid == 0) {
        int s = 0;
        for (int e = 0; e < E_NUM; e++) { base[e] = s; counts[e] = cnt[e]; s += cnt[e]; }
    }
}

#define MFMA(A, B, C) __builtin_amdgcn_mfma_f32_16x16x32_bf16(A, B, C, 0, 0, 0)

// SROA-friendly staging state: named members only, no dynamic indexing.
struct StA { uint4 a0, a1; };
struct StB { uint4 b0, b1, b2, b3; };

__device__ inline StA ldA(const __bf16* pA0, const __bf16* pA1, int k) {
    StA s;
    s.a0 = *(const uint4*)(pA0 + k);
    s.a1 = *(const uint4*)(pA1 + k);
    return s;
}
__device__ inline StB ldB(const __bf16* pB, int k) {
    StB s;
    s.b0 = *(const uint4*)(pB + k);
    s.b1 = *(const uint4*)(pB + k + 8);
    s.b2 = *(const uint4*)(pB + k + 16);
    s.b3 = *(const uint4*)(pB + k + 24);
    return s;
}
__device__ inline void stA(char* As, int aw0, int aw1, const StA& s) {
    *(uint4*)(As + aw0) = s.a0;
    *(uint4*)(As + aw1) = s.a1;
}
__device__ inline void stB(char* Bs, int bw0, int bw1, int bw2, int bw3, const StB& s) {
    *(uint4*)(Bs + bw0) = s.b0;
    *(uint4*)(Bs + bw1) = s.b1;
    *(uint4*)(Bs + bw2) = s.b2;
    *(uint4*)(Bs + bw3) = s.b3;
}

// ---- GEMM1: gate_up = x_g @ w13d^T, + SiLU -------------------------------
// M=64 x N=128(64 gate+64 up), BK=64, XCD-swizzled 1-D grid, reg pipeline
__global__ __launch_bounds__(256, 3) void gemm1_kernel(
    const __bf16* __restrict__ xbf,
    const __bf16* __restrict__ w13d,
    const int* __restrict__ counts,
    const int* __restrict__ base,
    const int* __restrict__ tok_list,
    __bf16* __restrict__ act)
{
    const int bx = blockIdx.x;
    const int xcd = bx & 7, t = bx >> 3;
    const int p = t % 12, m = t / 12;      // 12 pairs per XCD, 16 m rounds
    const int P = xcd + 8 * p;             // pair id in [0,96)
    const int nb = P % 12, e = P / 12;
    const int count = counts[e];
    const int m0 = m * 64;
    if (m0 >= count) return;
    const int n0 = nb * 64;
    const int abase = base[e];

    __shared__ union {
        struct { __bf16 Bs[2][128 * 64]; __bf16 As[2][64 * 64]; } s;  // 49152 B
        float gu[64 * 132];
    } u;
    __shared__ int tokS[64];

    const int tid = threadIdx.x;
    if (tid < 64) {
        int r = m0 + tid;
        tokS[tid] = (r < count) ? tok_list[e * T_TOK + r] : tok_list[e * T_TOK];
    }

    // B staging pointers (independent of tokS): issue B loads FIRST
    const int brow = tid >> 1, bg0 = (tid & 1) * 4;
    const int nB = (brow < 64) ? (n0 + brow) : (I_DIM + n0 + brow - 64);
    const __bf16* pB = w13d + ((size_t)e * 2 * I_DIM + nB) * H_DIM + bg0 * 8;
    const int bw0 = brow * 128 + (((bg0 + 0) ^ (brow & 7)) << 4);
    const int bw1 = brow * 128 + (((bg0 + 1) ^ (brow & 7)) << 4);
    const int bw2 = brow * 128 + (((bg0 + 2) ^ (brow & 7)) << 4);
    const int bw3 = brow * 128 + (((bg0 + 3) ^ (brow & 7)) << 4);

    StB XB = ldB(pB, 0);
    StB YB = ldB(pB, 64);
    __syncthreads();                       // tokS visible

    const int arow = tid >> 3, ag = tid & 7;
    const __bf16* pA0 = xbf + (size_t)tokS[arow] * H_DIM + ag * 8;
    const __bf16* pA1 = xbf + (size_t)tokS[arow + 32] * H_DIM + ag * 8;
    const int aw0 = arow * 128 + ((ag ^ (arow & 7)) << 4);
    const int aw1 = aw0 + 32 * 128;

    StA XA = ldA(pA0, pA1, 0);
    StA YA = ldA(pA0, pA1, 64);

    const int wid = tid >> 6, lane = tid & 63, lrow = lane & 15, quad = lane >> 4;
    int aoff[2][4], boff[2][2];
#pragma unroll
    for (int kk = 0; kk < 2; kk++) {
        int gph = ((kk * 4 + quad) ^ (lrow & 7)) << 4;
#pragma unroll
        for (int i = 0; i < 4; i++) aoff[kk][i] = (i * 16 + lrow) * 128 + gph;
#pragma unroll
        for (int j = 0; j < 2; j++) boff[kk][j] = (wid * 32 + j * 16 + lrow) * 128 + gph;
    }

    f32x4 acc[4][2];
#pragma unroll
    for (int i = 0; i < 4; i++)
#pragma unroll
        for (int j = 0; j < 2; j++) { f32x4 z = {0.f, 0.f, 0.f, 0.f}; acc[i][j] = z; }

    char* A0 = (char*)u.s.As[0]; char* A1 = (char*)u.s.As[1];
    char* B0 = (char*)u.s.Bs[0]; char* B1 = (char*)u.s.Bs[1];

    auto compute = [&](const char* Ab, const char* Bb) {
#pragma unroll
        for (int kk = 0; kk < 2; kk++) {
            bf16x8 b0 = *(const bf16x8*)(Bb + boff[kk][0]);
            bf16x8 b1 = *(const bf16x8*)(Bb + boff[kk][1]);
#pragma unroll
            for (int i = 0; i < 4; i++) {
                bf16x8 a = *(const bf16x8*)(Ab + aoff[kk][i]);
                acc[i][0] = MFMA(a, b0, acc[i][0]);
                acc[i][1] = MFMA(a, b1, acc[i][1]);
            }
        }
    };

    // pipeline: contents 0..15 (K = 16*64)
    stA(A0, aw0, aw1, XA); stB(B0, bw0, bw1, bw2, bw3, XB);
    XA = ldA(pA0, pA1, 128); XB = ldB(pB, 128);
    __syncthreads();

#pragma unroll
    for (int uu = 0; uu < 8; ++uu) {
        stA(A1, aw0, aw1, YA); stB(B1, bw0, bw1, bw2, bw3, YB);
        if (2 * uu + 3 < 16) { YA = ldA(pA0, pA1, (2 * uu + 3) * 64); YB = ldB(pB, (2 * uu + 3) * 64); }
        compute(A0, B0);
        __syncthreads();
        if (uu < 7) { stA(A0, aw0, aw1, XA); stB(B0, bw0, bw1, bw2, bw3, XB); }
        if (2 * uu + 4 < 16) { XA = ldA(pA0, pA1, (2 * uu + 4) * 64); XB = ldB(pB, (2 * uu + 4) * 64); }
        compute(A1, B1);
        __syncthreads();
    }

    // epilogue: staging dead; reuse union as gu
#pragma unroll
    for (int i = 0; i < 4; i++)
#pragma unroll
        for (int j = 0; j < 2; j++)
#pragma unroll
            for (int r = 0; r < 4; r++) {
                int mr = i * 16 + quad * 4 + r;
                int c = wid * 32 + j * 16 + lrow;
                u.gu[mr * 132 + c] = acc[i][j][r];
            }
    __syncthreads();

#pragma unroll
    for (int ii = 0; ii < 16; ii++) {
        int o = ii * 256 + tid;
        int mr = o >> 6, c = o & 63;
        if (m0 + mr < count) {
            float g  = u.gu[mr * 132 + c];
            float up = u.gu[mr * 132 + 64 + c];
            float a  = g / (1.0f + expf(-g)) * up;
            act[(size_t)(abase + m0 + mr) * I_DIM + n0 + c] = (__bf16)a;
        }
    }
}

// ---- GEMM2: out += w * (act @ w2d^T) -------------------------------------
// M=64 x N=128, BK=64, K-split x2 (atomic epilogue), XCD-swizzled grid
__global__ __launch_bounds__(256, 3) void gemm2_kernel(
    const __bf16* __restrict__ act,
    const __bf16* __restrict__ w2d,
    const int* __restrict__ counts,
    const int* __restrict__ base,
    const int* __restrict__ tok_list,
    const float* __restrict__ wt_list,
    float* __restrict__ out)
{
    const int bx = blockIdx.x;
    const int xcd = bx & 7, t = bx >> 3;
    const int kh = t & 1;                  // K half: [kh*384, kh*384+384)
    const int t2 = t >> 1;
    const int p = t2 & 7, m = t2 >> 3;     // 8 pairs per XCD, 16 m rounds
    const int P = xcd + 8 * p;             // pair id in [0,64)
    const int nb = P & 7, e = P >> 3;      // nb == xcd: n-slice pinned per XCD
    const int count = counts[e];
    const int m0 = m * 64;
    if (m0 >= count) return;
    const int n0 = nb * 128;
    const int abase = base[e];
    const int kb = kh * 384;

    __shared__ struct { __bf16 Bs[2][128 * 64]; __bf16 As[2][64 * 64]; } s;  // 49152 B

    const int tid = threadIdx.x;
    const int arow = tid >> 3, ag = tid & 7;
    int gr0 = abase + m0 + arow;      if (gr0 > 2 * T_TOK - 1) gr0 = 2 * T_TOK - 1;
    int gr1 = abase + m0 + arow + 32; if (gr1 > 2 * T_TOK - 1) gr1 = 2 * T_TOK - 1;
    const __bf16* pA0 = act + (size_t)gr0 * I_DIM + kb + ag * 8;
    const __bf16* pA1 = act + (size_t)gr1 * I_DIM + kb + ag * 8;
    const int aw0 = arow * 128 + ((ag ^ (arow & 7)) << 4);
    const int aw1 = aw0 + 32 * 128;

    const int brow = tid >> 1, bg0 = (tid & 1) * 4;
    const __bf16* pB = w2d + ((size_t)e * H_DIM + n0 + brow) * I_DIM + kb + bg0 * 8;
    const int bw0 = brow * 128 + (((bg0 + 0) ^ (brow & 7)) << 4);
    const int bw1 = brow * 128 + (((bg0 + 1) ^ (brow & 7)) << 4);
    const int bw2 = brow * 128 + (((bg0 + 2) ^ (brow & 7)) << 4);
    const int bw3 = brow * 128 + (((bg0 + 3) ^ (brow & 7)) << 4);

    const int wid = tid >> 6, lane = tid & 63, lrow = lane & 15, quad = lane >> 4;
    int aoff[2][4], boff[2][2];
#pragma unroll
    for (int kk = 0; kk < 2; kk++) {
        int gph = ((kk * 4 + quad) ^ (lrow & 7)) << 4;
#pragma unroll
        for (int i = 0; i < 4; i++) aoff[kk][i] = (i * 16 + lrow) * 128 + gph;
#pragma unroll
        for (int j = 0; j < 2; j++) boff[kk][j] = (wid * 32 + j * 16 + lrow) * 128 + gph;
    }

    f32x4 acc[4][2];
#pragma unroll
    for (int i = 0; i < 4; i++)
#pragma unroll
        for (int j = 0; j < 2; j++) { f32x4 z = {0.f, 0.f, 0.f, 0.f}; acc[i][j] = z; }

    char* A0 = (char*)s.As[0]; char* A1 = (char*)s.As[1];
    char* B0 = (char*)s.Bs[0]; char* B1 = (char*)s.Bs[1];

    auto compute = [&](const char* Ab, const char* Bb) {
#pragma unroll
        for (int kk = 0; kk < 2; kk++) {
            bf16x8 b0 = *(const bf16x8*)(Bb + boff[kk][0]);
            bf16x8 b1 = *(const bf16x8*)(Bb + boff[kk][1]);
#pragma unroll
            for (int i = 0; i < 4; i++) {
                bf16x8 a = *(const bf16x8*)(Ab + aoff[kk][i]);
                acc[i][0] = MFMA(a, b0, acc[i][0]);
                acc[i][1] = MFMA(a, b1, acc[i][1]);
            }
        }
    };

    // pipeline: contents 0..5 (K half = 6*64 = 384)
    StA XA = ldA(pA0, pA1, 0);
    StB XB = ldB(pB, 0);
    StA YA = ldA(pA0, pA1, 64);
    StB YB = ldB(pB, 64);
    stA(A0, aw0, aw1, XA); stB(B0, bw0, bw1, bw2, bw3, XB);
    XA = ldA(pA0, pA1, 128); XB = ldB(pB, 128);
    __syncthreads();

#pragma unroll
    for (int uu = 0; uu < 3; ++uu) {
        stA(A1, aw0, aw1, YA); stB(B1, bw0, bw1, bw2, bw3, YB);
        if (2 * uu + 3 < 6) { YA = ldA(pA0, pA1, (2 * uu + 3) * 64); YB = ldB(pB, (2 * uu + 3) * 64); }
        compute(A0, B0);
        __syncthreads();
        if (uu < 2) { stA(A0, aw0, aw1, XA); stB(B0, bw0, bw1, bw2, bw3, XB); }
        if (2 * uu + 4 < 6) { XA = ldA(pA0, pA1, (2 * uu + 4) * 64); XB = ldB(pB, (2 * uu + 4) * 64); }
        compute(A1, B1);
        __syncthreads();
    }

    // weighted atomic scatter
#pragma unroll
    for (int i = 0; i < 4; i++)
#pragma unroll
        for (int r = 0; r < 4; r++) {
            int mr = i * 16 + quad * 4 + r;
            if (m0 + mr < count) {
                int   tk = tok_list[e * T_TOK + m0 + mr];
                float w  = wt_list[e * T_TOK + m0 + mr];
#pragma unroll
                for (int j = 0; j < 2; j++) {
                    int h = n0 + wid * 32 + j * 16 + lrow;
                    atomicAdd(&out[(size_t)tk * H_DIM + h], w * acc[i][j][r]);
                }
            }
        }
}

extern "C" void kernel_launch(void* const* d_in, const int* in_sizes, int n_in,
                              void* d_out, int out_size, void* d_ws, size_t ws_size,
                              hipStream_t stream) {
    (void)in_sizes; (void)n_in; (void)out_size; (void)ws_size;
    const float* x      = (const float*)d_in[0];
    const float* logits = (const float*)d_in[1];
    const float* w13    = (const float*)d_in[2];
    const float* w13s   = (const float*)d_in[3];
    const float* w2     = (const float*)d_in[4];
    const float* w2s    = (const float*)d_in[5];
    float* out = (float*)d_out;

    char* ws = (char*)d_ws;
    int*    counts   = (int*)ws;                              // @0
    int*    base     = (int*)(ws + 128);                      // @128
    int*    tok_list = (int*)(ws + 256);                      // 32 KB
    float*  wt_list  = (float*)(ws + 256 + 32768);            // 32 KB
    __bf16* act      = (__bf16*)(ws + 65792);                 // 3 MB
    __bf16* xbf      = (__bf16*)(ws + 65792 + 3145728);       // 2 MB
    __bf16* w13d     = (__bf16*)(ws + 65792 + 3145728 + 2097152);            // 25.2 MB
    __bf16* w2d      = (__bf16*)(ws + 65792 + 3145728 + 2097152 + 25165824); // 12.6 MB

    prep_kernel<<<dim3(5121), 256, 0, stream>>>(
        w13, w13s, w2, w2s, x, (float4*)out, w13d, w2d, xbf,
        logits, counts, base, tok_list, wt_list);
    gemm1_kernel<<<dim3(1536), 256, 0, stream>>>(
        xbf, w13d, counts, base, tok_list, act);
    gemm2_kernel<<<dim3(2048), 256, 0, stream>>>(
        act, w2d, counts, base, tok_list, wt_list, out);
}

// Round 9
// 156.855 us; speedup vs baseline: 1.0027x; 1.0027x over previous
//
#include <hip/hip_runtime.h>

#define T_TOK 1024
#define H_DIM 1024
#define I_DIM 768
#define E_NUM 8

// dequant ranges (in 8-element groups)
#define G13 1572864   // 8*1536*1024/8
#define G2   786432   // 8*1024*768/8
#define GX   131072   // 1024*1024/8

typedef __bf16 bf16x8 __attribute__((ext_vector_type(8)));
typedef float  f32x4  __attribute__((ext_vector_type(4)));

__device__ inline bf16x8 cvt8(float4 a, float4 b, float s) {
    bf16x8 o;
    o[0] = (__bf16)(a.x * s); o[1] = (__bf16)(a.y * s);
    o[2] = (__bf16)(a.z * s); o[3] = (__bf16)(a.w * s);
    o[4] = (__bf16)(b.x * s); o[5] = (__bf16)(b.y * s);
    o[6] = (__bf16)(b.z * s); o[7] = (__bf16)(b.w * s);
    return o;
}

__device__ inline void w13_group(int g, const float* __restrict__ w13,
                                 const float* __restrict__ w13s,
                                 __bf16* __restrict__ w13d) {
    int k8 = g & 127;               // 128 groups per 1024-k row
    int row = g >> 7;               // e*1536 + n
    float s = w13s[(row << 3) | (k8 >> 4)];
    const float4* src = (const float4*)w13 + (size_t)g * 2;
    *(bf16x8*)(w13d + (size_t)g * 8) = cvt8(src[0], src[1], s);
}

__device__ inline void w2_group(int g2, const float* __restrict__ w2,
                                const float* __restrict__ w2s,
                                __bf16* __restrict__ w2d) {
    unsigned row = (unsigned)g2 / 96u;   // e*1024 + h (96 groups per 768-k row)
    int k8 = g2 - row * 96;
    float s = w2s[row * 6 + (k8 >> 4)];
    const float4* src = (const float4*)w2 + (size_t)g2 * 2;
    *(bf16x8*)(w2d + (size_t)g2 * 8) = cvt8(src[0], src[1], s);
}

// ---- prep1: w13 dequant + x convert + router (gemm1's dependencies only) -
__global__ __launch_bounds__(256) void prep1_kernel(
    const float* __restrict__ w13, const float* __restrict__ w13s,
    const float* __restrict__ x,   const float* __restrict__ logits,
    __bf16* __restrict__ w13d,     __bf16* __restrict__ xbf,
    int* __restrict__ counts, int* __restrict__ base,
    int* __restrict__ tok_list, float* __restrict__ wt_list)
{
    const int bx = blockIdx.x, tid = threadIdx.x;
    if (bx < 3072) {                       // 3072*512 == G13
        int g0 = bx * 512 + tid;
        w13_group(g0, w13, w13s, w13d);
        w13_group(g0 + 256, w13, w13s, w13d);
        return;
    }
    if (bx < 3328) {                       // 256*512 == GX
        int gx = (bx - 3072) * 512 + tid;
#pragma unroll
        for (int q = 0; q < 2; q++) {
            int g = gx + q * 256;
            const float4* src = (const float4*)x + (size_t)g * 2;
            *(bf16x8*)(xbf + (size_t)g * 8) = cvt8(src[0], src[1], 1.0f);
        }
        return;
    }
    // ---- router block: top-2 of 8, renormalized weights ----
    __shared__ int cnt[E_NUM];
    if (tid < E_NUM) cnt[tid] = 0;
    __syncthreads();
#pragma unroll
    for (int tt = 0; tt < 4; tt++) {
        int t = tid + tt * 256;
        float l[E_NUM];
#pragma unroll
        for (int e = 0; e < E_NUM; e++) l[e] = logits[t * E_NUM + e];
        int e0 = 0; float m0 = l[0];
#pragma unroll
        for (int e = 1; e < E_NUM; e++) if (l[e] > m0) { m0 = l[e]; e0 = e; }
        int e1 = -1; float m1 = -3e38f;
#pragma unroll
        for (int e = 0; e < E_NUM; e++) if (e != e0 && l[e] > m1) { m1 = l[e]; e1 = e; }
        float w0 = 1.0f / (1.0f + expf(m1 - m0));
        float w1 = 1.0f - w0;
        int p0 = atomicAdd(&cnt[e0], 1);
        tok_list[e0 * T_TOK + p0] = t;
        wt_list[e0 * T_TOK + p0] = w0;
        int p1 = atomicAdd(&cnt[e1], 1);
        tok_list[e1 * T_TOK + p1] = t;
        wt_list[e1 * T_TOK + p1] = w1;
    }
    __syncthreads();
    if (tid == 0) {
        int s = 0;
        for (int e = 0; e < E_NUM; e++) { base[e] = s; counts[e] = cnt[e]; s += cnt[e]; }
    }
}

#define MFMA(A, B, C) __builtin_amdgcn_mfma_f32_16x16x32_bf16(A, B, C, 0, 0, 0)

// SROA-friendly staging state: named members only, no dynamic indexing.
struct StA { uint4 a0, a1; };
struct StB { uint4 b0, b1, b2, b3; };

__device__ inline StA ldA(const __bf16* pA0, const __bf16* pA1, int k) {
    StA s;
    s.a0 = *(const uint4*)(pA0 + k);
    s.a1 = *(const uint4*)(pA1 + k);
    return s;
}
__device__ inline StB ldB(const __bf16* pB, int k) {
    StB s;
    s.b0 = *(const uint4*)(pB + k);
    s.b1 = *(const uint4*)(pB + k + 8);
    s.b2 = *(const uint4*)(pB + k + 16);
    s.b3 = *(const uint4*)(pB + k + 24);
    return s;
}
__device__ inline void stA(char* As, int aw0, int aw1, const StA& s) {
    *(uint4*)(As + aw0) = s.a0;
    *(uint4*)(As + aw1) = s.a1;
}
__device__ inline void stB(char* Bs, int bw0, int bw1, int bw2, int bw3, const StB& s) {
    *(uint4*)(Bs + bw0) = s.b0;
    *(uint4*)(Bs + bw1) = s.b1;
    *(uint4*)(Bs + bw2) = s.b2;
    *(uint4*)(Bs + bw3) = s.b3;
}

// ---- GEMM1 (+fused w2 dequant & out zeroing in extra blocks) -------------
// blocks [0,1536): M=64 x N=128(64 gate+64 up), BK=64, XCD-swizzled, reg pipeline
// blocks [1536,3072): w2 fp32->bf16 dequant stream (fills gemm latency bubbles)
// blocks [3072,3328): zero out
__global__ __launch_bounds__(256, 3) void gemm1_kernel(
    const __bf16* __restrict__ xbf,
    const __bf16* __restrict__ w13d,
    const int* __restrict__ counts,
    const int* __restrict__ base,
    const int* __restrict__ tok_list,
    __bf16* __restrict__ act,
    const float* __restrict__ w2, const float* __restrict__ w2s,
    __bf16* __restrict__ w2d, float4* __restrict__ out4)
{
    const int bx = blockIdx.x;
    const int tid = threadIdx.x;
    if (bx >= 1536) {
        if (bx < 3072) {                   // 1536*512 == G2
            int g0 = (bx - 1536) * 512 + tid;
            w2_group(g0, w2, w2s, w2d);
            w2_group(g0 + 256, w2, w2s, w2d);
        } else {                           // 256 blocks zero 262144 float4s
            int i0 = (bx - 3072) * 512 + tid;
            float4 z = make_float4(0.f, 0.f, 0.f, 0.f);
            out4[i0] = z; out4[i0 + 256] = z;
        }
        return;
    }

    const int xcd = bx & 7, t = bx >> 3;
    const int p = t % 12, m = t / 12;      // 12 pairs per XCD, 16 m rounds
    const int P = xcd + 8 * p;             // pair id in [0,96)
    const int nb = P % 12, e = P / 12;
    const int count = counts[e];
    const int m0 = m * 64;
    if (m0 >= count) return;
    const int n0 = nb * 64;
    const int abase = base[e];

    __shared__ union {
        struct { __bf16 Bs[2][128 * 64]; __bf16 As[2][64 * 64]; } s;  // 49152 B
        float gu[64 * 132];
    } u;
    __shared__ int tokS[64];

    if (tid < 64) {
        int r = m0 + tid;
        tokS[tid] = (r < count) ? tok_list[e * T_TOK + r] : tok_list[e * T_TOK];
    }

    // B staging pointers (independent of tokS): issue B loads FIRST
    const int brow = tid >> 1, bg0 = (tid & 1) * 4;
    const int nB = (brow < 64) ? (n0 + brow) : (I_DIM + n0 + brow - 64);
    const __bf16* pB = w13d + ((size_t)e * 2 * I_DIM + nB) * H_DIM + bg0 * 8;
    const int bw0 = brow * 128 + (((bg0 + 0) ^ (brow & 7)) << 4);
    const int bw1 = brow * 128 + (((bg0 + 1) ^ (brow & 7)) << 4);
    const int bw2 = brow * 128 + (((bg0 + 2) ^ (brow & 7)) << 4);
    const int bw3 = brow * 128 + (((bg0 + 3) ^ (brow & 7)) << 4);

    StB XB = ldB(pB, 0);
    StB YB = ldB(pB, 64);
    __syncthreads();                       // tokS visible

    const int arow = tid >> 3, ag = tid & 7;
    const __bf16* pA0 = xbf + (size_t)tokS[arow] * H_DIM + ag * 8;
    const __bf16* pA1 = xbf + (size_t)tokS[arow + 32] * H_DIM + ag * 8;
    const int aw0 = arow * 128 + ((ag ^ (arow & 7)) << 4);
    const int aw1 = aw0 + 32 * 128;

    StA XA = ldA(pA0, pA1, 0);
    StA YA = ldA(pA0, pA1, 64);

    const int wid = tid >> 6, lane = tid & 63, lrow = lane & 15, quad = lane >> 4;
    int aoff[2][4], boff[2][2];
#pragma unroll
    for (int kk = 0; kk < 2; kk++) {
        int gph = ((kk * 4 + quad) ^ (lrow & 7)) << 4;
#pragma unroll
        for (int i = 0; i < 4; i++) aoff[kk][i] = (i * 16 + lrow) * 128 + gph;
#pragma unroll
        for (int j = 0; j < 2; j++) boff[kk][j] = (wid * 32 + j * 16 + lrow) * 128 + gph;
    }

    f32x4 acc[4][2];
#pragma unroll
    for (int i = 0; i < 4; i++)
#pragma unroll
        for (int j = 0; j < 2; j++) { f32x4 z = {0.f, 0.f, 0.f, 0.f}; acc[i][j] = z; }

    char* A0 = (char*)u.s.As[0]; char* A1 = (char*)u.s.As[1];
    char* B0 = (char*)u.s.Bs[0]; char* B1 = (char*)u.s.Bs[1];

    auto compute = [&](const char* Ab, const char* Bb) {
#pragma unroll
        for (int kk = 0; kk < 2; kk++) {
            bf16x8 b0 = *(const bf16x8*)(Bb + boff[kk][0]);
            bf16x8 b1 = *(const bf16x8*)(Bb + boff[kk][1]);
#pragma unroll
            for (int i = 0; i < 4; i++) {
                bf16x8 a = *(const bf16x8*)(Ab + aoff[kk][i]);
                acc[i][0] = MFMA(a, b0, acc[i][0]);
                acc[i][1] = MFMA(a, b1, acc[i][1]);
            }
        }
    };

    // pipeline: contents 0..15 (K = 16*64)
    stA(A0, aw0, aw1, XA); stB(B0, bw0, bw1, bw2, bw3, XB);
    XA = ldA(pA0, pA1, 128); XB = ldB(pB, 128);
    __syncthreads();

#pragma unroll
    for (int uu = 0; uu < 8; ++uu) {
        stA(A1, aw0, aw1, YA); stB(B1, bw0, bw1, bw2, bw3, YB);
        if (2 * uu + 3 < 16) { YA = ldA(pA0, pA1, (2 * uu + 3) * 64); YB = ldB(pB, (2 * uu + 3) * 64); }
        compute(A0, B0);
        __syncthreads();
        if (uu < 7) { stA(A0, aw0, aw1, XA); stB(B0, bw0, bw1, bw2, bw3, XB); }
        if (2 * uu + 4 < 16) { XA = ldA(pA0, pA1, (2 * uu + 4) * 64); XB = ldB(pB, (2 * uu + 4) * 64); }
        compute(A1, B1);
        __syncthreads();
    }

    // epilogue: staging dead; reuse union as gu
#pragma unroll
    for (int i = 0; i < 4; i++)
#pragma unroll
        for (int j = 0; j < 2; j++)
#pragma unroll
            for (int r = 0; r < 4; r++) {
                int mr = i * 16 + quad * 4 + r;
                int c = wid * 32 + j * 16 + lrow;
                u.gu[mr * 132 + c] = acc[i][j][r];
            }
    __syncthreads();

#pragma unroll
    for (int ii = 0; ii < 16; ii++) {
        int o = ii * 256 + tid;
        int mr = o >> 6, c = o & 63;
        if (m0 + mr < count) {
            float g  = u.gu[mr * 132 + c];
            float up = u.gu[mr * 132 + 64 + c];
            float a  = g / (1.0f + expf(-g)) * up;
            act[(size_t)(abase + m0 + mr) * I_DIM + n0 + c] = (__bf16)a;
        }
    }
}

// ---- GEMM2: out += w * (act @ w2d^T) -------------------------------------
// M=64 x N=128, BK=64, K-split x2 (atomic epilogue), XCD-swizzled grid
__global__ __launch_bounds__(256, 3) void gemm2_kernel(
    const __bf16* __restrict__ act,
    const __bf16* __restrict__ w2d,
    const int* __restrict__ counts,
    const int* __restrict__ base,
    const int* __restrict__ tok_list,
    const float* __restrict__ wt_list,
    float* __restrict__ out)
{
    const int bx = blockIdx.x;
    const int xcd = bx & 7, t = bx >> 3;
    const int kh = t & 1;                  // K half: [kh*384, kh*384+384)
    const int t2 = t >> 1;
    const int p = t2 & 7, m = t2 >> 3;     // 8 pairs per XCD, 16 m rounds
    const int P = xcd + 8 * p;             // pair id in [0,64)
    const int nb = P & 7, e = P >> 3;      // nb == xcd: n-slice pinned per XCD
    const int count = counts[e];
    const int m0 = m * 64;
    if (m0 >= count) return;
    const int n0 = nb * 128;
    const int abase = base[e];
    const int kb = kh * 384;

    __shared__ struct { __bf16 Bs[2][128 * 64]; __bf16 As[2][64 * 64]; } s;  // 49152 B

    const int tid = threadIdx.x;
    const int arow = tid >> 3, ag = tid & 7;
    int gr0 = abase + m0 + arow;      if (gr0 > 2 * T_TOK - 1) gr0 = 2 * T_TOK - 1;
    int gr1 = abase + m0 + arow + 32; if (gr1 > 2 * T_TOK - 1) gr1 = 2 * T_TOK - 1;
    const __bf16* pA0 = act + (size_t)gr0 * I_DIM + kb + ag * 8;
    const __bf16* pA1 = act + (size_t)gr1 * I_DIM + kb + ag * 8;
    const int aw0 = arow * 128 + ((ag ^ (arow & 7)) << 4);
    const int aw1 = aw0 + 32 * 128;

    const int brow = tid >> 1, bg0 = (tid & 1) * 4;
    const __bf16* pB = w2d + ((size_t)e * H_DIM + n0 + brow) * I_DIM + kb + bg0 * 8;
    const int bw0 = brow * 128 + (((bg0 + 0) ^ (brow & 7)) << 4);
    const int bw1 = brow * 128 + (((bg0 + 1) ^ (brow & 7)) << 4);
    const int bw2 = brow * 128 + (((bg0 + 2) ^ (brow & 7)) << 4);
    const int bw3 = brow * 128 + (((bg0 + 3) ^ (brow & 7)) << 4);

    const int wid = tid >> 6, lane = tid & 63, lrow = lane & 15, quad = lane >> 4;
    int aoff[2][4], boff[2][2];
#pragma unroll
    for (int kk = 0; kk < 2; kk++) {
        int gph = ((kk * 4 + quad) ^ (lrow & 7)) << 4;
#pragma unroll
        for (int i = 0; i < 4; i++) aoff[kk][i] = (i * 16 + lrow) * 128 + gph;
#pragma unroll
        for (int j = 0; j < 2; j++) boff[kk][j] = (wid * 32 + j * 16 + lrow) * 128 + gph;
    }

    f32x4 acc[4][2];
#pragma unroll
    for (int i = 0; i < 4; i++)
#pragma unroll
        for (int j = 0; j < 2; j++) { f32x4 z = {0.f, 0.f, 0.f, 0.f}; acc[i][j] = z; }

    char* A0 = (char*)s.As[0]; char* A1 = (char*)s.As[1];
    char* B0 = (char*)s.Bs[0]; char* B1 = (char*)s.Bs[1];

    auto compute = [&](const char* Ab, const char* Bb) {
#pragma unroll
        for (int kk = 0; kk < 2; kk++) {
            bf16x8 b0 = *(const bf16x8*)(Bb + boff[kk][0]);
            bf16x8 b1 = *(const bf16x8*)(Bb + boff[kk][1]);
#pragma unroll
            for (int i = 0; i < 4; i++) {
                bf16x8 a = *(const bf16x8*)(Ab + aoff[kk][i]);
                acc[i][0] = MFMA(a, b0, acc[i][0]);
                acc[i][1] = MFMA(a, b1, acc[i][1]);
            }
        }
    };

    // pipeline: contents 0..5 (K half = 6*64 = 384)
    StA XA = ldA(pA0, pA1, 0);
    StB XB = ldB(pB, 0);
    StA YA = ldA(pA0, pA1, 64);
    StB YB = ldB(pB, 64);
    stA(A0, aw0, aw1, XA); stB(B0, bw0, bw1, bw2, bw3, XB);
    XA = ldA(pA0, pA1, 128); XB = ldB(pB, 128);
    __syncthreads();

#pragma unroll
    for (int uu = 0; uu < 3; ++uu) {
        stA(A1, aw0, aw1, YA); stB(B1, bw0, bw1, bw2, bw3, YB);
        if (2 * uu + 3 < 6) { YA = ldA(pA0, pA1, (2 * uu + 3) * 64); YB = ldB(pB, (2 * uu + 3) * 64); }
        compute(A0, B0);
        __syncthreads();
        if (uu < 2) { stA(A0, aw0, aw1, XA); stB(B0, bw0, bw1, bw2, bw3, XB); }
        if (2 * uu + 4 < 6) { XA = ldA(pA0, pA1, (2 * uu + 4) * 64); XB = ldB(pB, (2 * uu + 4) * 64); }
        compute(A1, B1);
        __syncthreads();
    }

    // weighted atomic scatter
#pragma unroll
    for (int i = 0; i < 4; i++)
#pragma unroll
        for (int r = 0; r < 4; r++) {
            int mr = i * 16 + quad * 4 + r;
            if (m0 + mr < count) {
                int   tk = tok_list[e * T_TOK + m0 + mr];
                float w  = wt_list[e * T_TOK + m0 + mr];
#pragma unroll
                for (int j = 0; j < 2; j++) {
                    int h = n0 + wid * 32 + j * 16 + lrow;
                    atomicAdd(&out[(size_t)tk * H_DIM + h], w * acc[i][j][r]);
                }
            }
        }
}

extern "C" void kernel_launch(void* const* d_in, const int* in_sizes, int n_in,
                              void* d_out, int out_size, void* d_ws, size_t ws_size,
                              hipStream_t stream) {
    (void)in_sizes; (void)n_in; (void)out_size; (void)ws_size;
    const float* x      = (const float*)d_in[0];
    const float* logits = (const float*)d_in[1];
    const float* w13    = (const float*)d_in[2];
    const float* w13s   = (const float*)d_in[3];
    const float* w2     = (const float*)d_in[4];
    const float* w2s    = (const float*)d_in[5];
    float* out = (float*)d_out;

    char* ws = (char*)d_ws;
    int*    counts   = (int*)ws;                              // @0
    int*    base     = (int*)(ws + 128);                      // @128
    int*    tok_list = (int*)(ws + 256);                      // 32 KB
    float*  wt_list  = (float*)(ws + 256 + 32768);            // 32 KB
    __bf16* act      = (__bf16*)(ws + 65792);                 // 3 MB
    __bf16* xbf      = (__bf16*)(ws + 65792 + 3145728);       // 2 MB
    __bf16* w13d     = (__bf16*)(ws + 65792 + 3145728 + 2097152);            // 25.2 MB
    __bf16* w2d      = (__bf16*)(ws + 65792 + 3145728 + 2097152 + 25165824); // 12.6 MB

    prep1_kernel<<<dim3(3329), 256, 0, stream>>>(
        w13, w13s, x, logits, w13d, xbf, counts, base, tok_list, wt_list);
    gemm1_kernel<<<dim3(3328), 256, 0, stream>>>(
        xbf, w13d, counts, base, tok_list, act, w2, w2s, w2d, (float4*)out);
    gemm2_kernel<<<dim3(2048), 256, 0, stream>>>(
        act, w2d, counts, base, tok_list, wt_list, out);
}